// Round 1
// baseline (370.725 us; speedup 1.0000x reference)
//
#include <hip/hip_runtime.h>
#include <hip/hip_bf16.h>
#include <stdint.h>

#define B_   4
#define S_   2048
#define H_   16
#define HD_  64
#define D_   1024

typedef short  short8 __attribute__((ext_vector_type(8)));
typedef float  f32x4  __attribute__((ext_vector_type(4)));

__device__ __forceinline__ unsigned short f2bf(float f) {
    union { float f; unsigned u; } v; v.f = f;
    unsigned r = v.u + 0x7fffu + ((v.u >> 16) & 1u);
    return (unsigned short)(r >> 16);
}

// ---------------- fp32 -> bf16 convert (vectorized) ----------------
__global__ __launch_bounds__(256) void k_cvt(const float* __restrict__ in,
                                             unsigned short* __restrict__ out) {
    int i = (blockIdx.x * 256 + threadIdx.x) * 4;
    float4 f = *(const float4*)(in + i);
    ushort4 o;
    o.x = f2bf(f.x); o.y = f2bf(f.y); o.z = f2bf(f.z); o.w = f2bf(f.w);
    *(ushort4*)(out + i) = o;
}

// ---------- transpose + convert: in[K][N] f32 -> out[N][K] bf16 ----------
__global__ __launch_bounds__(256) void k_transpose_cvt(const float* __restrict__ in,
                                                       unsigned short* __restrict__ out,
                                                       int K, int N) {
    __shared__ float tile[32][33];
    int n0 = blockIdx.x * 32, k0 = blockIdx.y * 32;
    int tx = threadIdx.x, ty = threadIdx.y;
#pragma unroll
    for (int i = 0; i < 32; i += 8)
        tile[ty + i][tx] = in[(size_t)(k0 + ty + i) * N + n0 + tx];
    __syncthreads();
#pragma unroll
    for (int i = 0; i < 32; i += 8)
        out[(size_t)(n0 + ty + i) * K + k0 + tx] = f2bf(tile[tx][ty + i]);
}

__device__ __forceinline__ void async_load16(const unsigned short* g, unsigned short* l) {
    __builtin_amdgcn_global_load_lds(
        (const __attribute__((address_space(1))) unsigned int*)g,
        (__attribute__((address_space(3))) unsigned int*)l, 16, 0, 0);
}

// ---------------- bf16 GEMM: C[m][n] = A[m][k] * BT[n][k] + bias ----------------
// EPI 0: scatter to Q (scaled 0.125), K [B,H,S,64], V^T [B,H,64,S] as bf16
// EPI 1: fp32 output += bias
template <int EPI>
__global__ __launch_bounds__(256) void k_gemm(const unsigned short* __restrict__ A,
                                              const unsigned short* __restrict__ BT,
                                              const float* __restrict__ bias,
                                              float* __restrict__ outf,
                                              unsigned short* __restrict__ qb,
                                              unsigned short* __restrict__ kb,
                                              unsigned short* __restrict__ vtb,
                                              int M, int N, int K) {
    __shared__ __attribute__((aligned(16))) unsigned short As[128 * 32];
    __shared__ __attribute__((aligned(16))) unsigned short Bs[128 * 32];
    const int tid = threadIdx.x, wave = tid >> 6, lane = tid & 63;
    const int m0 = blockIdx.y * 128, n0 = blockIdx.x * 128;
    const int wr = wave >> 1, wc = wave & 1;

    f32x4 acc[4][4] = {};

    for (int kt = 0; kt < K; kt += 32) {
#pragma unroll
        for (int p = 0; p < 2; p++) {
            int chunk = p * 4 + wave;            // 8 chunks of 1024B per 8KB tile
            int off   = chunk * 1024 + lane * 16;
            int row   = off >> 6;                // 64B per row (32 bf16)
            int col   = (off & 63) >> 1;
            async_load16(A  + (size_t)(m0 + row) * K + kt + col, As + chunk * 512);
            async_load16(BT + (size_t)(n0 + row) * K + kt + col, Bs + chunk * 512);
        }
        __syncthreads();
        short8 af[4], bf[4];
#pragma unroll
        for (int i = 0; i < 4; i++) {
            af[i] = *(const short8*)(As + (wr * 64 + i * 16 + (lane & 15)) * 32 + (lane >> 4) * 8);
            bf[i] = *(const short8*)(Bs + (wc * 64 + i * 16 + (lane & 15)) * 32 + (lane >> 4) * 8);
        }
#pragma unroll
        for (int i = 0; i < 4; i++)
#pragma unroll
            for (int j = 0; j < 4; j++)
                acc[i][j] = __builtin_amdgcn_mfma_f32_16x16x32_bf16(af[i], bf[j], acc[i][j], 0, 0, 0);
        __syncthreads();
    }

#pragma unroll
    for (int i = 0; i < 4; i++) {
#pragma unroll
        for (int j = 0; j < 4; j++) {
            int n = n0 + wc * 64 + j * 16 + (lane & 15);
            float bv = bias[n];
#pragma unroll
            for (int r = 0; r < 4; r++) {
                int m = m0 + wr * 64 + i * 16 + ((lane >> 4) << 2) + r;
                float val = acc[i][j][r] + bv;
                if (EPI == 0) {
                    int part = n >> 10, rem = n & 1023;
                    int h = rem >> 6, d = rem & 63;
                    int b = m >> 11, s = m & 2047;
                    size_t bh = (size_t)(b * 16 + h);
                    if (part == 0)      qb[(bh * S_ + s) * HD_ + d] = f2bf(val * 0.125f);
                    else if (part == 1) kb[(bh * S_ + s) * HD_ + d] = f2bf(val);
                    else                vtb[(bh * HD_ + d) * S_ + s] = f2bf(val);
                } else {
                    outf[(size_t)m * N + n] = val;
                }
            }
        }
    }
}

// ---------------- causal flash attention, bf16 MFMA ----------------
// grid: (S/64, B*H); block 256 (4 waves x 16 q-rows)
__global__ __launch_bounds__(256) void k_attn(const unsigned short* __restrict__ Q,
                                              const unsigned short* __restrict__ Kg,
                                              const unsigned short* __restrict__ VT,
                                              unsigned short* __restrict__ Z) {
    __shared__ __attribute__((aligned(16))) unsigned short Ks[64 * 72];
    __shared__ __attribute__((aligned(16))) unsigned short Vs[64 * 72];
    __shared__ __attribute__((aligned(16))) unsigned short Ps[4][16 * 72];
    const int tid = threadIdx.x, wave = tid >> 6, lane = tid & 63;
    const int qtile = blockIdx.x;
    const int bh = blockIdx.y;
    const int q0 = qtile * 64;
    const int qw = q0 + wave * 16;
    const int b = bh >> 4, h = bh & 15;

    short8 qf[2];
    {
        const unsigned short* qp = Q + ((size_t)bh * S_ + qw + (lane & 15)) * HD_ + (lane >> 4) * 8;
        qf[0] = *(const short8*)qp;
        qf[1] = *(const short8*)(qp + 32);
    }
    float m_r[4], l_r[4];
    f32x4 oacc[4] = {};
#pragma unroll
    for (int r = 0; r < 4; r++) { m_r[r] = -1e30f; l_r[r] = 0.f; }

    const int nkv = qtile + 1;
    for (int t = 0; t < nkv; t++) {
        const int t0 = t * 64;
#pragma unroll
        for (int p = 0; p < 2; p++) {
            int li = p * 256 + tid;          // 512 x 16B units per tile
            int row = li >> 3, col = (li & 7) * 8;
            *(short8*)(Ks + row * 72 + col) =
                *(const short8*)(Kg + ((size_t)bh * S_ + t0 + row) * HD_ + col);
            *(short8*)(Vs + row * 72 + col) =
                *(const short8*)(VT + ((size_t)bh * HD_ + row) * S_ + t0 + col);
        }
        __syncthreads();

        f32x4 s[4] = {};
#pragma unroll
        for (int nt = 0; nt < 4; nt++) {
            const unsigned short* kp = Ks + (nt * 16 + (lane & 15)) * 72 + (lane >> 4) * 8;
            s[nt] = __builtin_amdgcn_mfma_f32_16x16x32_bf16(qf[0], *(const short8*)kp, s[nt], 0, 0, 0);
            s[nt] = __builtin_amdgcn_mfma_f32_16x16x32_bf16(qf[1], *(const short8*)(kp + 32), s[nt], 0, 0, 0);
        }
        if (t == qtile) {   // diagonal block: mask t_local > q_local
#pragma unroll
            for (int nt = 0; nt < 4; nt++) {
                int tl = nt * 16 + (lane & 15);
#pragma unroll
                for (int r = 0; r < 4; r++) {
                    int ql = wave * 16 + ((lane >> 4) << 2) + r;
                    if (tl > ql) s[nt][r] = -1e30f;
                }
            }
        }

        float mx[4], pscale[4], rsum[4];
#pragma unroll
        for (int r = 0; r < 4; r++)
            mx[r] = fmaxf(fmaxf(s[0][r], s[1][r]), fmaxf(s[2][r], s[3][r]));
#pragma unroll
        for (int d = 1; d < 16; d <<= 1)
#pragma unroll
            for (int r = 0; r < 4; r++)
                mx[r] = fmaxf(mx[r], __shfl_xor(mx[r], d));
#pragma unroll
        for (int r = 0; r < 4; r++) {
            float mn = fmaxf(m_r[r], mx[r]);
            pscale[r] = __expf(m_r[r] - mn);
            m_r[r] = mn;
            rsum[r] = 0.f;
        }
#pragma unroll
        for (int nt = 0; nt < 4; nt++)
#pragma unroll
            for (int r = 0; r < 4; r++) {
                float p = __expf(s[nt][r] - m_r[r]);
                s[nt][r] = p;
                rsum[r] += p;
            }
#pragma unroll
        for (int d = 1; d < 16; d <<= 1)
#pragma unroll
            for (int r = 0; r < 4; r++)
                rsum[r] += __shfl_xor(rsum[r], d);
#pragma unroll
        for (int r = 0; r < 4; r++)
            l_r[r] = l_r[r] * pscale[r] + rsum[r];
#pragma unroll
        for (int dt = 0; dt < 4; dt++)
#pragma unroll
            for (int r = 0; r < 4; r++)
                oacc[dt][r] *= pscale[r];

        // P (C-layout) -> per-wave LDS -> A-layout frags
        unsigned short* pw = &Ps[wave][0];
#pragma unroll
        for (int nt = 0; nt < 4; nt++)
#pragma unroll
            for (int r = 0; r < 4; r++)
                pw[(((lane >> 4) << 2) + r) * 72 + nt * 16 + (lane & 15)] = f2bf(s[nt][r]);
        __syncthreads();
#pragma unroll
        for (int kk = 0; kk < 2; kk++) {
            short8 pf = *(const short8*)(pw + (lane & 15) * 72 + kk * 32 + (lane >> 4) * 8);
#pragma unroll
            for (int dt = 0; dt < 4; dt++) {
                short8 vf = *(const short8*)(Vs + (dt * 16 + (lane & 15)) * 72 + kk * 32 + (lane >> 4) * 8);
                oacc[dt] = __builtin_amdgcn_mfma_f32_16x16x32_bf16(pf, vf, oacc[dt], 0, 0, 0);
            }
        }
        __syncthreads();
    }

#pragma unroll
    for (int dt = 0; dt < 4; dt++) {
#pragma unroll
        for (int r = 0; r < 4; r++) {
            int sq = qw + ((lane >> 4) << 2) + r;
            int dg = h * HD_ + dt * 16 + (lane & 15);
            Z[((size_t)b * S_ + sq) * D_ + dg] = f2bf(oacc[dt][r] / l_r[r]);
        }
    }
}

extern "C" void kernel_launch(void* const* d_in, const int* in_sizes, int n_in,
                              void* d_out, int out_size, void* d_ws, size_t ws_size,
                              hipStream_t stream) {
    const float* x     = (const float*)d_in[0];
    const float* w_qkv = (const float*)d_in[1];
    const float* b_qkv = (const float*)d_in[2];
    const float* w_out = (const float*)d_in[3];
    const float* b_out = (const float*)d_in[4];
    float* out = (float*)d_out;

    char* ws = (char*)d_ws;
    unsigned short* xb    = (unsigned short*)(ws + 0);          // 16 MB (aliased as Z later)
    unsigned short* wqkvT = (unsigned short*)(ws + 16777216);   // 6 MB
    unsigned short* woutT = (unsigned short*)(ws + 23068672);   // 2 MB
    unsigned short* qb    = (unsigned short*)(ws + 25165824);   // 16 MB
    unsigned short* kb    = (unsigned short*)(ws + 41943040);   // 16 MB
    unsigned short* vtb   = (unsigned short*)(ws + 58720256);   // 16 MB  -> 75.5 MB total
    unsigned short* zb    = xb;  // safe alias: xb consumed by QKV GEMM before attn writes zb

    k_cvt<<<8192, 256, 0, stream>>>(x, xb);
    k_transpose_cvt<<<dim3(96, 32), dim3(32, 8), 0, stream>>>(w_qkv, wqkvT, 1024, 3072);
    k_transpose_cvt<<<dim3(32, 32), dim3(32, 8), 0, stream>>>(w_out, woutT, 1024, 1024);
    k_gemm<0><<<dim3(24, 64), 256, 0, stream>>>(xb, wqkvT, b_qkv, nullptr, qb, kb, vtb,
                                                8192, 3072, 1024);
    k_attn<<<dim3(32, 64), 256, 0, stream>>>(qb, kb, vtb, zb);
    k_gemm<1><<<dim3(8, 64), 256, 0, stream>>>(zb, woutT, b_out, out, nullptr, nullptr, nullptr,
                                               8192, 1024, 1024);
}

// Round 3
// 263.645 us; speedup vs baseline: 1.4062x; 1.4062x over previous
//
#include <hip/hip_runtime.h>
#include <hip/hip_bf16.h>
#include <stdint.h>

#define B_   4
#define S_   2048
#define H_   16
#define HD_  64
#define D_   1024

typedef short  short8  __attribute__((ext_vector_type(8)));
typedef float  f32x4   __attribute__((ext_vector_type(4)));
typedef float  f32x16  __attribute__((ext_vector_type(16)));

__device__ __forceinline__ unsigned short f2bf(float f) {
    union { float f; unsigned u; } v; v.f = f;
    unsigned r = v.u + 0x7fffu + ((v.u >> 16) & 1u);
    return (unsigned short)(r >> 16);
}

#if __has_builtin(__builtin_amdgcn_exp2f)
#define EXP2(x) __builtin_amdgcn_exp2f(x)
#else
#define EXP2(x) exp2f(x)
#endif

__device__ __forceinline__ unsigned cvtpk(float lo, float hi) {
    unsigned r;
    asm("v_cvt_pk_bf16_f32 %0, %1, %2" : "=v"(r) : "v"(lo), "v"(hi));
    return r;
}

__device__ __forceinline__ float bq(float v, int srclane) {
    return __int_as_float(__builtin_amdgcn_ds_bpermute(srclane << 2, __float_as_int(v)));
}

#define MFMA32(a, b, c) __builtin_amdgcn_mfma_f32_32x32x16_bf16(a, b, c, 0, 0, 0)

// ---------------- fp32 -> bf16 convert (vectorized) ----------------
__global__ __launch_bounds__(256) void k_cvt(const float* __restrict__ in,
                                             unsigned short* __restrict__ out) {
    int i = (blockIdx.x * 256 + threadIdx.x) * 4;
    float4 f = *(const float4*)(in + i);
    ushort4 o;
    o.x = f2bf(f.x); o.y = f2bf(f.y); o.z = f2bf(f.z); o.w = f2bf(f.w);
    *(ushort4*)(out + i) = o;
}

// ---------- transpose + convert: in[K][N] f32 -> out[N][K] bf16 ----------
__global__ __launch_bounds__(256) void k_transpose_cvt(const float* __restrict__ in,
                                                       unsigned short* __restrict__ out,
                                                       int K, int N) {
    __shared__ float tile[32][33];
    int n0 = blockIdx.x * 32, k0 = blockIdx.y * 32;
    int tx = threadIdx.x, ty = threadIdx.y;
#pragma unroll
    for (int i = 0; i < 32; i += 8)
        tile[ty + i][tx] = in[(size_t)(k0 + ty + i) * N + n0 + tx];
    __syncthreads();
#pragma unroll
    for (int i = 0; i < 32; i += 8)
        out[(size_t)(n0 + ty + i) * K + k0 + tx] = f2bf(tile[tx][ty + i]);
}

__device__ __forceinline__ void async_load16(const unsigned short* g, unsigned short* l) {
    __builtin_amdgcn_global_load_lds(
        (const __attribute__((address_space(1))) unsigned int*)g,
        (__attribute__((address_space(3))) unsigned int*)l, 16, 0, 0);
}

// ---------------- bf16 GEMM: C[m][n] = A[m][k] * BT[n][k] + bias ----------------
// EPI 0: scatter to Q (scaled by 0.125*log2(e)), K [B,H,S,64], V^T [B,H,64,S]
// EPI 1: fp32 output += bias
template <int EPI>
__global__ __launch_bounds__(256) void k_gemm(const unsigned short* __restrict__ A,
                                              const unsigned short* __restrict__ BT,
                                              const float* __restrict__ bias,
                                              float* __restrict__ outf,
                                              unsigned short* __restrict__ qb,
                                              unsigned short* __restrict__ kb,
                                              unsigned short* __restrict__ vtb,
                                              int M, int N, int K) {
    __shared__ __attribute__((aligned(16))) unsigned short As[128 * 32];
    __shared__ __attribute__((aligned(16))) unsigned short Bs[128 * 32];
    const int tid = threadIdx.x, wave = tid >> 6, lane = tid & 63;
    const int m0 = blockIdx.y * 128, n0 = blockIdx.x * 128;
    const int wr = wave >> 1, wc = wave & 1;

    f32x4 acc[4][4] = {};

    for (int kt = 0; kt < K; kt += 32) {
#pragma unroll
        for (int p = 0; p < 2; p++) {
            int chunk = p * 4 + wave;
            int off   = chunk * 1024 + lane * 16;
            int row   = off >> 6;
            int col   = (off & 63) >> 1;
            async_load16(A  + (size_t)(m0 + row) * K + kt + col, As + chunk * 512);
            async_load16(BT + (size_t)(n0 + row) * K + kt + col, Bs + chunk * 512);
        }
        __syncthreads();
        short8 af[4], bf[4];
#pragma unroll
        for (int i = 0; i < 4; i++) {
            af[i] = *(const short8*)(As + (wr * 64 + i * 16 + (lane & 15)) * 32 + (lane >> 4) * 8);
            bf[i] = *(const short8*)(Bs + (wc * 64 + i * 16 + (lane & 15)) * 32 + (lane >> 4) * 8);
        }
#pragma unroll
        for (int i = 0; i < 4; i++)
#pragma unroll
            for (int j = 0; j < 4; j++)
                acc[i][j] = __builtin_amdgcn_mfma_f32_16x16x32_bf16(af[i], bf[j], acc[i][j], 0, 0, 0);
        __syncthreads();
    }

#pragma unroll
    for (int i = 0; i < 4; i++) {
#pragma unroll
        for (int j = 0; j < 4; j++) {
            int n = n0 + wc * 64 + j * 16 + (lane & 15);
            float bv = bias[n];
#pragma unroll
            for (int r = 0; r < 4; r++) {
                int m = m0 + wr * 64 + i * 16 + ((lane >> 4) << 2) + r;
                float val = acc[i][j][r] + bv;
                if (EPI == 0) {
                    int part = n >> 10, rem = n & 1023;
                    int h = rem >> 6, d = rem & 63;
                    int b = m >> 11, s = m & 2047;
                    size_t bh = (size_t)(b * 16 + h);
                    // fold 1/sqrt(64) and log2(e) into Q so softmax runs in exp2 domain
                    if (part == 0)      qb[(bh * S_ + s) * HD_ + d] = f2bf(val * 0.18033688011112042f);
                    else if (part == 1) kb[(bh * S_ + s) * HD_ + d] = f2bf(val);
                    else                vtb[(bh * HD_ + d) * S_ + s] = f2bf(val);
                } else {
                    outf[(size_t)m * N + n] = val;
                }
            }
        }
    }
}

// ---------------- causal flash attention: 32x32 MFMA, LDS-free, barrier-free ----------------
// grid: 1024 blocks (8 xcd x 8 bh x 16 qtiles), block 256 (4 waves x 32 q-rows)
// Swapped QK^T: sT = mfma(K, Q) -> C-layout col=lane&31 = q (lane-local softmax),
// row = crow(r,hi) = (r&3)+8*(r>>2)+4*hi = t  [verified m74/m101].
// P -> PV A-frag via cvt_pk + shfl_xor(32) + select (m214-verified mapping, robust exchange).
__global__ __launch_bounds__(256) void k_attn(const unsigned short* __restrict__ Qg,
                                              const unsigned short* __restrict__ Kg,
                                              const unsigned short* __restrict__ Vt,
                                              unsigned short* __restrict__ Z) {
    const int i = blockIdx.x;
    const int bh = (i & 7) * 8 + ((i >> 3) & 7);   // 8 bh per XCD -> K/V fits one L2
    const int qtile = 15 - (i >> 6);               // longest blocks launch first
    const int tid = threadIdx.x, wave = tid >> 6, lane = tid & 63;
    const int c = lane & 31, hi = lane >> 5;
    const int qbase = qtile * 128 + wave * 32;
    const int b = bh >> 4, h = bh & 15;

    const unsigned short* Qb = Qg + ((size_t)bh * S_ + qbase + c) * HD_ + hi * 8;
    const unsigned short* Kb = Kg + ((size_t)bh * S_ + c) * HD_ + hi * 8;
    const unsigned short* Vb = Vt + ((size_t)bh * HD_ + c) * S_ + hi * 8;

    short8 qf[4];
#pragma unroll
    for (int kd = 0; kd < 4; kd++)
        qf[kd] = *(const short8*)(Qb + kd * 16);

    f32x16 oacc[2] = {};                 // O[q=crow(r,hi)][d = dt*32 + c]
    float m_r = -1e30f, l_r = 0.f;

    const int nkv = (qbase >> 5) + 1;
    for (int tt = 0; tt < nkv; tt++) {
        const int t0 = tt * 32;
        short8 kf[4];
#pragma unroll
        for (int kd = 0; kd < 4; kd++)
            kf[kd] = *(const short8*)(Kb + (size_t)t0 * HD_ + kd * 16);

        f32x16 sT = {};                  // sT[t=crow(r,hi)][q=c]
#pragma unroll
        for (int kd = 0; kd < 4; kd++)
            sT = MFMA32(kf[kd], qf[kd], sT);

        short8 vf[2][2];                 // B[col=d=dt*32+c][k=t=ks*16+hi*8+j]
#pragma unroll
        for (int dt = 0; dt < 2; dt++)
#pragma unroll
            for (int ks = 0; ks < 2; ks++)
                vf[dt][ks] = *(const short8*)(Vb + (size_t)(dt * 32) * S_ + t0 + ks * 16);

        if (t0 == qbase) {               // diagonal tile: mask t_local > q_local
#pragma unroll
            for (int r = 0; r < 16; r++) {
                int tl = (r & 3) + 8 * (r >> 2) + 4 * hi;
                if (tl > c) sT[r] = -1e30f;
            }
        }

        float mx = sT[0];
#pragma unroll
        for (int r = 1; r < 16; r++) mx = fmaxf(mx, sT[r]);
        mx = fmaxf(mx, __shfl_xor(mx, 32));
        if (__any(mx > m_r)) {
            float mn = fmaxf(m_r, mx);
            float ps = EXP2(m_r - mn);
            m_r = mn;
            l_r *= ps;
#pragma unroll
            for (int r = 0; r < 16; r++) {
                float psb = bq(ps, (r & 3) + 8 * (r >> 2) + 4 * hi);
                oacc[0][r] *= psb;
                oacc[1][r] *= psb;
            }
        }
        float rs = 0.f;
#pragma unroll
        for (int r = 0; r < 16; r++) {
            float p = EXP2(sT[r] - m_r);
            sT[r] = p;
            rs += p;
        }
        rs += __shfl_xor(rs, 32);
        l_r += rs;

        // pack P to bf16 pairs: pk[i] = (p[2i], p[2i+1]) = t-pair (4hi+2i', 4hi+2i'+1) per 8-block
        unsigned pk0 = cvtpk(sT[0],  sT[1]);
        unsigned pk1 = cvtpk(sT[2],  sT[3]);
        unsigned pk2 = cvtpk(sT[4],  sT[5]);
        unsigned pk3 = cvtpk(sT[6],  sT[7]);
        unsigned pk4 = cvtpk(sT[8],  sT[9]);
        unsigned pk5 = cvtpk(sT[10], sT[11]);
        unsigned pk6 = cvtpk(sT[12], sT[13]);
        unsigned pk7 = cvtpk(sT[14], sT[15]);
        // cross-half exchange (lane <-> lane^32), then select by hi:
        unsigned q0 = (unsigned)__shfl_xor((int)pk0, 32);
        unsigned q1 = (unsigned)__shfl_xor((int)pk1, 32);
        unsigned q2 = (unsigned)__shfl_xor((int)pk2, 32);
        unsigned q3 = (unsigned)__shfl_xor((int)pk3, 32);
        unsigned q4 = (unsigned)__shfl_xor((int)pk4, 32);
        unsigned q5 = (unsigned)__shfl_xor((int)pk5, 32);
        unsigned q6 = (unsigned)__shfl_xor((int)pk6, 32);
        unsigned q7 = (unsigned)__shfl_xor((int)pk7, 32);
        union { unsigned u[4]; short8 s; } pa0, pa1;
        // A-frag word j holds t = 8*hi + 2j, 8*hi + 2j+1 (ks*16 block offset)
        pa0.u[0] = hi ? q2 : pk0;  pa0.u[1] = hi ? q3 : pk1;
        pa0.u[2] = hi ? pk2 : q0;  pa0.u[3] = hi ? pk3 : q1;
        pa1.u[0] = hi ? q6 : pk4;  pa1.u[1] = hi ? q7 : pk5;
        pa1.u[2] = hi ? pk6 : q4;  pa1.u[3] = hi ? pk7 : q5;

        oacc[0] = MFMA32(pa0.s, vf[0][0], oacc[0]);
        oacc[1] = MFMA32(pa0.s, vf[1][0], oacc[1]);
        oacc[0] = MFMA32(pa1.s, vf[0][1], oacc[0]);
        oacc[1] = MFMA32(pa1.s, vf[1][1], oacc[1]);
    }

#pragma unroll
    for (int r = 0; r < 16; r++) {
        int crow = (r & 3) + 8 * (r >> 2) + 4 * hi;
        float inv = __builtin_amdgcn_rcpf(bq(l_r, crow));
        int q = qbase + crow;
        Z[((size_t)b * S_ + q) * D_ + h * HD_ + c]      = f2bf(oacc[0][r] * inv);
        Z[((size_t)b * S_ + q) * D_ + h * HD_ + 32 + c] = f2bf(oacc[1][r] * inv);
    }
}

extern "C" void kernel_launch(void* const* d_in, const int* in_sizes, int n_in,
                              void* d_out, int out_size, void* d_ws, size_t ws_size,
                              hipStream_t stream) {
    const float* x     = (const float*)d_in[0];
    const float* w_qkv = (const float*)d_in[1];
    const float* b_qkv = (const float*)d_in[2];
    const float* w_out = (const float*)d_in[3];
    const float* b_out = (const float*)d_in[4];
    float* out = (float*)d_out;

    char* ws = (char*)d_ws;
    unsigned short* xb    = (unsigned short*)(ws + 0);          // 16 MB (aliased as Z later)
    unsigned short* wqkvT = (unsigned short*)(ws + 16777216);   // 6 MB
    unsigned short* woutT = (unsigned short*)(ws + 23068672);   // 2 MB
    unsigned short* qb    = (unsigned short*)(ws + 25165824);   // 16 MB
    unsigned short* kb    = (unsigned short*)(ws + 41943040);   // 16 MB
    unsigned short* vtb   = (unsigned short*)(ws + 58720256);   // 16 MB
    unsigned short* zb    = xb;  // safe alias: xb consumed by QKV GEMM before attn writes zb

    k_cvt<<<8192, 256, 0, stream>>>(x, xb);
    k_transpose_cvt<<<dim3(96, 32), dim3(32, 8), 0, stream>>>(w_qkv, wqkvT, 1024, 3072);
    k_transpose_cvt<<<dim3(32, 32), dim3(32, 8), 0, stream>>>(w_out, woutT, 1024, 1024);
    k_gemm<0><<<dim3(24, 64), 256, 0, stream>>>(xb, wqkvT, b_qkv, nullptr, qb, kb, vtb,
                                                8192, 3072, 1024);
    k_attn<<<1024, 256, 0, stream>>>(qb, kb, vtb, zb);
    k_gemm<1><<<dim3(8, 64), 256, 0, stream>>>(zb, woutT, b_out, out, nullptr, nullptr, nullptr,
                                               8192, 1024, 1024);
}

// Round 4
// 263.243 us; speedup vs baseline: 1.4083x; 1.0015x over previous
//
#include <hip/hip_runtime.h>
#include <hip/hip_bf16.h>
#include <stdint.h>

#define B_   4
#define S_   2048
#define H_   16
#define HD_  64
#define D_   1024

typedef short  short8  __attribute__((ext_vector_type(8)));
typedef float  f32x4   __attribute__((ext_vector_type(4)));
typedef float  f32x16  __attribute__((ext_vector_type(16)));

__device__ __forceinline__ unsigned short f2bf(float f) {
    union { float f; unsigned u; } v; v.f = f;
    unsigned r = v.u + 0x7fffu + ((v.u >> 16) & 1u);
    return (unsigned short)(r >> 16);
}

#if __has_builtin(__builtin_amdgcn_exp2f)
#define EXP2(x) __builtin_amdgcn_exp2f(x)
#else
#define EXP2(x) exp2f(x)
#endif

__device__ __forceinline__ unsigned cvtpk(float lo, float hi) {
    unsigned r;
    asm("v_cvt_pk_bf16_f32 %0, %1, %2" : "=v"(r) : "v"(lo), "v"(hi));
    return r;
}

__device__ __forceinline__ float bq(float v, int srclane) {
    return __int_as_float(__builtin_amdgcn_ds_bpermute(srclane << 2, __float_as_int(v)));
}

#define MFMA32(a, b, c) __builtin_amdgcn_mfma_f32_32x32x16_bf16(a, b, c, 0, 0, 0)

// ---------------- fp32 -> bf16 convert (vectorized) ----------------
__global__ __launch_bounds__(256) void k_cvt(const float* __restrict__ in,
                                             unsigned short* __restrict__ out) {
    int i = (blockIdx.x * 256 + threadIdx.x) * 4;
    float4 f = *(const float4*)(in + i);
    ushort4 o;
    o.x = f2bf(f.x); o.y = f2bf(f.y); o.z = f2bf(f.z); o.w = f2bf(f.w);
    *(ushort4*)(out + i) = o;
}

// ---------- transpose + convert: in[K][N] f32 -> out[N][K] bf16 ----------
__global__ __launch_bounds__(256) void k_transpose_cvt(const float* __restrict__ in,
                                                       unsigned short* __restrict__ out,
                                                       int K, int N) {
    __shared__ float tile[32][33];
    int n0 = blockIdx.x * 32, k0 = blockIdx.y * 32;
    int tx = threadIdx.x, ty = threadIdx.y;
#pragma unroll
    for (int i = 0; i < 32; i += 8)
        tile[ty + i][tx] = in[(size_t)(k0 + ty + i) * N + n0 + tx];
    __syncthreads();
#pragma unroll
    for (int i = 0; i < 32; i += 8)
        out[(size_t)(n0 + ty + i) * K + k0 + tx] = f2bf(tile[tx][ty + i]);
}

__device__ __forceinline__ void async_load16(const unsigned short* g, unsigned short* l) {
    __builtin_amdgcn_global_load_lds(
        (const __attribute__((address_space(1))) unsigned int*)g,
        (__attribute__((address_space(3))) unsigned int*)l, 16, 0, 0);
}

// ---------------- bf16 GEMM: C[m][n] = A[m][k] * BT[n][k] + bias ----------------
// EPI 0: scatter to Q (scaled by 0.125*log2(e)), K [B,H,S,64], V^T [B,H,64,S]
// EPI 1: fp32 output += bias
template <int EPI>
__global__ __launch_bounds__(256) void k_gemm(const unsigned short* __restrict__ A,
                                              const unsigned short* __restrict__ BT,
                                              const float* __restrict__ bias,
                                              float* __restrict__ outf,
                                              unsigned short* __restrict__ qb,
                                              unsigned short* __restrict__ kb,
                                              unsigned short* __restrict__ vtb,
                                              int M, int N, int K) {
    __shared__ __attribute__((aligned(16))) unsigned short As[128 * 32];
    __shared__ __attribute__((aligned(16))) unsigned short Bs[128 * 32];
    const int tid = threadIdx.x, wave = tid >> 6, lane = tid & 63;
    const int m0 = blockIdx.y * 128, n0 = blockIdx.x * 128;
    const int wr = wave >> 1, wc = wave & 1;

    f32x4 acc[4][4] = {};

    for (int kt = 0; kt < K; kt += 32) {
#pragma unroll
        for (int p = 0; p < 2; p++) {
            int chunk = p * 4 + wave;
            int off   = chunk * 1024 + lane * 16;
            int row   = off >> 6;
            int col   = (off & 63) >> 1;
            async_load16(A  + (size_t)(m0 + row) * K + kt + col, As + chunk * 512);
            async_load16(BT + (size_t)(n0 + row) * K + kt + col, Bs + chunk * 512);
        }
        __syncthreads();
        short8 af[4], bf[4];
#pragma unroll
        for (int i = 0; i < 4; i++) {
            af[i] = *(const short8*)(As + (wr * 64 + i * 16 + (lane & 15)) * 32 + (lane >> 4) * 8);
            bf[i] = *(const short8*)(Bs + (wc * 64 + i * 16 + (lane & 15)) * 32 + (lane >> 4) * 8);
        }
#pragma unroll
        for (int i = 0; i < 4; i++)
#pragma unroll
            for (int j = 0; j < 4; j++)
                acc[i][j] = __builtin_amdgcn_mfma_f32_16x16x32_bf16(af[i], bf[j], acc[i][j], 0, 0, 0);
        __syncthreads();
    }

#pragma unroll
    for (int i = 0; i < 4; i++) {
#pragma unroll
        for (int j = 0; j < 4; j++) {
            int n = n0 + wc * 64 + j * 16 + (lane & 15);
            float bv = bias[n];
#pragma unroll
            for (int r = 0; r < 4; r++) {
                int m = m0 + wr * 64 + i * 16 + ((lane >> 4) << 2) + r;
                float val = acc[i][j][r] + bv;
                if (EPI == 0) {
                    int part = n >> 10, rem = n & 1023;
                    int h = rem >> 6, d = rem & 63;
                    int b = m >> 11, s = m & 2047;
                    size_t bh = (size_t)(b * 16 + h);
                    // fold 1/sqrt(64) and log2(e) into Q so softmax runs in exp2 domain
                    if (part == 0)      qb[(bh * S_ + s) * HD_ + d] = f2bf(val * 0.18033688011112042f);
                    else if (part == 1) kb[(bh * S_ + s) * HD_ + d] = f2bf(val);
                    else                vtb[(bh * HD_ + d) * S_ + s] = f2bf(val);
                } else {
                    outf[(size_t)m * N + n] = val;
                }
            }
        }
    }
}

// ---------------- causal flash attention: 32x32 MFMA, LDS-free, 1-wave blocks ----------------
// grid: 4096 blocks x 64 threads (1 wave = one 32-row q-strip of one bh).
// Longest strips first; bh-octet pinned per XCD for L2 locality.
// Swapped QK^T: sT = mfma(K, Q), col=lane&31 = q -> lane-local softmax.
// K prefetch (rotation) hides L2 latency inside the wave.
__global__ __launch_bounds__(64) void k_attn(const unsigned short* __restrict__ Qg,
                                             const unsigned short* __restrict__ Kg,
                                             const unsigned short* __restrict__ Vt,
                                             unsigned short* __restrict__ Z) {
    const int i = blockIdx.x;
    const int bh = (i & 7) * 8 + ((i >> 3) & 7);   // 8 bh per XCD -> K/V fits one L2
    const int strip = 63 - (i >> 6);               // longest strips launch first
    const int lane = threadIdx.x & 63;
    const int c = lane & 31, hi = lane >> 5;
    const int qbase = strip * 32;
    const int b = bh >> 4, h = bh & 15;

    const unsigned short* Qb = Qg + ((size_t)bh * S_ + qbase + c) * HD_ + hi * 8;
    const unsigned short* Kb = Kg + ((size_t)bh * S_ + c) * HD_ + hi * 8;
    const unsigned short* Vb = Vt + ((size_t)bh * HD_ + c) * S_ + hi * 8;

    short8 qf[4];
#pragma unroll
    for (int kd = 0; kd < 4; kd++)
        qf[kd] = *(const short8*)(Qb + kd * 16);

    f32x16 oacc[2] = {};                 // O[q=crow(r,hi)][d = dt*32 + c]
    float m_r = -1e30f, l_r = 0.f;

    const int nkv = strip + 1;
    short8 kf_cur[4], kf_nxt[4];
#pragma unroll
    for (int kd = 0; kd < 4; kd++)
        kf_cur[kd] = *(const short8*)(Kb + kd * 16);

    for (int tt = 0; tt < nkv; tt++) {
        const int t0 = tt * 32;
        // prefetch next tile's K (clamped -> no branch; result unused on last iter)
        const int tn = (tt + 1 < nkv) ? (t0 + 32) : t0;
#pragma unroll
        for (int kd = 0; kd < 4; kd++)
            kf_nxt[kd] = *(const short8*)(Kb + (size_t)tn * HD_ + kd * 16);

        f32x16 sT = {};                  // sT[t=crow(r,hi)][q=c]
#pragma unroll
        for (int kd = 0; kd < 4; kd++)
            sT = MFMA32(kf_cur[kd], qf[kd], sT);

        short8 vf[2][2];                 // B[col=d=dt*32+c][k=t=ks*16+hi*8+j]
#pragma unroll
        for (int dt = 0; dt < 2; dt++)
#pragma unroll
            for (int ks = 0; ks < 2; ks++)
                vf[dt][ks] = *(const short8*)(Vb + (size_t)(dt * 32) * S_ + t0 + ks * 16);

        if (t0 == qbase) {               // diagonal tile: mask t_local > q_local
#pragma unroll
            for (int r = 0; r < 16; r++) {
                int tl = (r & 3) + 8 * (r >> 2) + 4 * hi;
                if (tl > c) sT[r] = -1e30f;
            }
        }

        float mx = sT[0];
#pragma unroll
        for (int r = 1; r < 16; r++) mx = fmaxf(mx, sT[r]);
        mx = fmaxf(mx, __shfl_xor(mx, 32));
        if (__any(mx > m_r)) {
            float mn = fmaxf(m_r, mx);
            float ps = EXP2(m_r - mn);
            m_r = mn;
            l_r *= ps;
#pragma unroll
            for (int r = 0; r < 16; r++) {
                float psb = bq(ps, (r & 3) + 8 * (r >> 2) + 4 * hi);
                oacc[0][r] *= psb;
                oacc[1][r] *= psb;
            }
        }
        float rs = 0.f;
#pragma unroll
        for (int r = 0; r < 16; r++) {
            float p = EXP2(sT[r] - m_r);
            sT[r] = p;
            rs += p;
        }
        rs += __shfl_xor(rs, 32);
        l_r += rs;

        // pack P to bf16 pairs (t-pairs within 8-blocks), then cross-half exchange
        unsigned pk0 = cvtpk(sT[0],  sT[1]);
        unsigned pk1 = cvtpk(sT[2],  sT[3]);
        unsigned pk2 = cvtpk(sT[4],  sT[5]);
        unsigned pk3 = cvtpk(sT[6],  sT[7]);
        unsigned pk4 = cvtpk(sT[8],  sT[9]);
        unsigned pk5 = cvtpk(sT[10], sT[11]);
        unsigned pk6 = cvtpk(sT[12], sT[13]);
        unsigned pk7 = cvtpk(sT[14], sT[15]);
        unsigned q0 = (unsigned)__shfl_xor((int)pk0, 32);
        unsigned q1 = (unsigned)__shfl_xor((int)pk1, 32);
        unsigned q2 = (unsigned)__shfl_xor((int)pk2, 32);
        unsigned q3 = (unsigned)__shfl_xor((int)pk3, 32);
        unsigned q4 = (unsigned)__shfl_xor((int)pk4, 32);
        unsigned q5 = (unsigned)__shfl_xor((int)pk5, 32);
        unsigned q6 = (unsigned)__shfl_xor((int)pk6, 32);
        unsigned q7 = (unsigned)__shfl_xor((int)pk7, 32);
        union { unsigned u[4]; short8 s; } pa0, pa1;
        // A-frag word j holds t = 8*hi + 2j, 8*hi + 2j+1 (ks*16 block offset)
        pa0.u[0] = hi ? q2 : pk0;  pa0.u[1] = hi ? q3 : pk1;
        pa0.u[2] = hi ? pk2 : q0;  pa0.u[3] = hi ? pk3 : q1;
        pa1.u[0] = hi ? q6 : pk4;  pa1.u[1] = hi ? q7 : pk5;
        pa1.u[2] = hi ? pk6 : q4;  pa1.u[3] = hi ? pk7 : q5;

        oacc[0] = MFMA32(pa0.s, vf[0][0], oacc[0]);
        oacc[1] = MFMA32(pa0.s, vf[1][0], oacc[1]);
        oacc[0] = MFMA32(pa1.s, vf[0][1], oacc[0]);
        oacc[1] = MFMA32(pa1.s, vf[1][1], oacc[1]);

#pragma unroll
        for (int kd = 0; kd < 4; kd++)
            kf_cur[kd] = kf_nxt[kd];
    }

#pragma unroll
    for (int r = 0; r < 16; r++) {
        int crow = (r & 3) + 8 * (r >> 2) + 4 * hi;
        float inv = __builtin_amdgcn_rcpf(bq(l_r, crow));
        int q = qbase + crow;
        Z[((size_t)b * S_ + q) * D_ + h * HD_ + c]      = f2bf(oacc[0][r] * inv);
        Z[((size_t)b * S_ + q) * D_ + h * HD_ + 32 + c] = f2bf(oacc[1][r] * inv);
    }
}

extern "C" void kernel_launch(void* const* d_in, const int* in_sizes, int n_in,
                              void* d_out, int out_size, void* d_ws, size_t ws_size,
                              hipStream_t stream) {
    const float* x     = (const float*)d_in[0];
    const float* w_qkv = (const float*)d_in[1];
    const float* b_qkv = (const float*)d_in[2];
    const float* w_out = (const float*)d_in[3];
    const float* b_out = (const float*)d_in[4];
    float* out = (float*)d_out;

    char* ws = (char*)d_ws;
    unsigned short* xb    = (unsigned short*)(ws + 0);          // 16 MB (aliased as Z later)
    unsigned short* wqkvT = (unsigned short*)(ws + 16777216);   // 6 MB
    unsigned short* woutT = (unsigned short*)(ws + 23068672);   // 2 MB
    unsigned short* qb    = (unsigned short*)(ws + 25165824);   // 16 MB
    unsigned short* kb    = (unsigned short*)(ws + 41943040);   // 16 MB
    unsigned short* vtb   = (unsigned short*)(ws + 58720256);   // 16 MB
    unsigned short* zb    = xb;  // safe alias: xb consumed by QKV GEMM before attn writes zb

    k_cvt<<<8192, 256, 0, stream>>>(x, xb);
    k_transpose_cvt<<<dim3(96, 32), dim3(32, 8), 0, stream>>>(w_qkv, wqkvT, 1024, 3072);
    k_transpose_cvt<<<dim3(32, 32), dim3(32, 8), 0, stream>>>(w_out, woutT, 1024, 1024);
    k_gemm<0><<<dim3(24, 64), 256, 0, stream>>>(xb, wqkvT, b_qkv, nullptr, qb, kb, vtb,
                                                8192, 3072, 1024);
    k_attn<<<4096, 64, 0, stream>>>(qb, kb, vtb, zb);
    k_gemm<1><<<dim3(8, 64), 256, 0, stream>>>(zb, woutT, b_out, out, nullptr, nullptr, nullptr,
                                               8192, 1024, 1024);
}